// Round 1
// baseline (160.032 us; speedup 1.0000x reference)
//
#include <hip/hip_runtime.h>
#include <math.h>

constexpr int kMaxF   = 32;
constexpr int kFtOut  = 256;   // floats per row = 64 float4
constexpr int kNumFFT = 640;

__device__ __forceinline__ void fma4(float4& acc, float v, const float4& a, const float4& b) {
    acc.x = fmaf(v, a.x + b.x, acc.x);
    acc.y = fmaf(v, a.y + b.y, acc.y);
    acc.z = fmaf(v, a.z + b.z, acc.z);
    acc.w = fmaf(v, a.w + b.w, acc.w);
}

__device__ __forceinline__ float clip01(float x) {
    return fminf(fmaxf(x, 0.0f), 1.0f);
}

// One wave (64 lanes) per batch element. Lane l owns output dims [4l, 4l+4).
__global__ __launch_bounds__(256) void nnue_halfkp_kernel(
    const float* __restrict__ values,
    const int*   __restrict__ stm_idx,
    const int*   __restrict__ nstm_idx,
    const float* __restrict__ ft_w,
    const float* __restrict__ ft_b,
    const float* __restrict__ fft_w,
    const float* __restrict__ fft_b,
    const float* __restrict__ out_w,
    const float* __restrict__ out_b,
    float*       __restrict__ out,
    int batch)
{
    const int gtid = blockIdx.x * blockDim.x + threadIdx.x;
    const int b    = gtid >> 6;
    const int lane = threadIdx.x & 63;
    if (b >= batch) return;

    // Stash this element's values + indices in registers for shfl broadcast:
    // lanes [0,32): values[b][lane] and stm_idx[b][lane]
    // lanes [32,64): nstm_idx[b][lane-32]
    float v_reg = 0.0f;
    int   i_reg = 0;
    if (lane < kMaxF) {
        v_reg = values[b * kMaxF + lane];
        i_reg = stm_idx[b * kMaxF + lane];
    } else {
        i_reg = nstm_idx[b * kMaxF + (lane - kMaxF)];
    }

    const float4* ftw4  = reinterpret_cast<const float4*>(ft_w);   // row stride 64 float4
    const float4* fftw4 = reinterpret_cast<const float4*>(fft_w);

    // Accumulators start at ft_b + fft_b (fused: the two embed-sums are added
    // before clip, so one accumulator per side suffices).
    const float4 fb  = reinterpret_cast<const float4*>(ft_b)[lane];
    const float4 ffb = reinterpret_cast<const float4*>(fft_b)[lane];
    float4 acc_s = make_float4(fb.x + ffb.x, fb.y + ffb.y, fb.z + ffb.z, fb.w + ffb.w);
    float4 acc_n = acc_s;

#pragma unroll 8
    for (int f = 0; f < kMaxF; ++f) {
        const float v  = __shfl(v_reg, f, 64);
        const int   is = __shfl(i_reg, f, 64);
        const int   in = __shfl(i_reg, f + kMaxF, 64);
        const float4 as = ftw4[is * 64 + lane];
        const float4 bs = fftw4[(is % kNumFFT) * 64 + lane];
        const float4 an = ftw4[in * 64 + lane];
        const float4 bn = fftw4[(in % kNumFFT) * 64 + lane];
        fma4(acc_s, v, as, bs);
        fma4(acc_n, v, an, bn);
    }

    // hidden = clip(concat(stm, nstm), 0, 1); partial dot with out_w.
    const float4* ow4 = reinterpret_cast<const float4*>(out_w);  // 128 float4: [0,64)=stm, [64,128)=nstm
    const float4 ws = ow4[lane];
    const float4 wn = ow4[64 + lane];

    float p = clip01(acc_s.x) * ws.x + clip01(acc_s.y) * ws.y
            + clip01(acc_s.z) * ws.z + clip01(acc_s.w) * ws.w
            + clip01(acc_n.x) * wn.x + clip01(acc_n.y) * wn.y
            + clip01(acc_n.z) * wn.z + clip01(acc_n.w) * wn.w;

    // wave-64 butterfly reduce
    #pragma unroll
    for (int off = 32; off > 0; off >>= 1)
        p += __shfl_down(p, off, 64);

    if (lane == 0) {
        const float x = p + out_b[0];
        out[b] = 1.0f / (1.0f + expf(-x));
    }
}

extern "C" void kernel_launch(void* const* d_in, const int* in_sizes, int n_in,
                              void* d_out, int out_size, void* d_ws, size_t ws_size,
                              hipStream_t stream) {
    const float* values = (const float*)d_in[0];
    const int*   stm    = (const int*)  d_in[1];
    const int*   nstm   = (const int*)  d_in[2];
    const float* ft_w   = (const float*)d_in[3];
    const float* ft_b   = (const float*)d_in[4];
    const float* fft_w  = (const float*)d_in[5];
    const float* fft_b  = (const float*)d_in[6];
    const float* out_w  = (const float*)d_in[7];
    const float* out_b  = (const float*)d_in[8];
    float* out = (float*)d_out;

    const int batch   = in_sizes[0] / kMaxF;   // 8192
    const int threads = 256;                   // 4 waves/block, 1 batch element per wave
    const int blocks  = (batch * 64 + threads - 1) / threads;

    hipLaunchKernelGGL(nnue_halfkp_kernel, dim3(blocks), dim3(threads), 0, stream,
                       values, stm, nstm, ft_w, ft_b, fft_w, fft_b, out_w, out_b,
                       out, batch);
}

// Round 2
// 130.532 us; speedup vs baseline: 1.2260x; 1.2260x over previous
//
#include <hip/hip_runtime.h>
#include <math.h>

constexpr int kMaxF   = 32;
constexpr int kFtOut  = 256;
constexpr int kNumFFT = 640;
constexpr int kNumFT  = 40960;

__device__ __forceinline__ float clip01(float x) {
    return fminf(fmaxf(x, 0.0f), 1.0f);
}

// fp32 -> bf16 (round-to-nearest-even), as raw ushort
__device__ __forceinline__ unsigned short f2bf(float x) {
    unsigned int u = __float_as_uint(x);
    unsigned int r = (u + 0x7fffu + ((u >> 16) & 1u)) >> 16;
    return (unsigned short)r;
}

// ---- prep: comb[i][d] = bf16(ft_w[i][d] + fft_w[i % 640][d]) ----
__global__ __launch_bounds__(256) void prep_comb_kernel(
    const float* __restrict__ ft_w,
    const float* __restrict__ fft_w,
    unsigned short* __restrict__ comb,
    int total4)   // kNumFT*kFtOut/4
{
    const int t = blockIdx.x * blockDim.x + threadIdx.x;
    if (t >= total4) return;
    const int elem = t << 2;          // flat fp32 element index
    const int row  = elem >> 8;       // / kFtOut
    const int d    = elem & (kFtOut - 1);
    const float4 a = *reinterpret_cast<const float4*>(ft_w + elem);
    const float4 b = *reinterpret_cast<const float4*>(fft_w + (row % kNumFFT) * kFtOut + d);
    ushort4 o;
    o.x = f2bf(a.x + b.x);
    o.y = f2bf(a.y + b.y);
    o.z = f2bf(a.z + b.z);
    o.w = f2bf(a.w + b.w);
    *reinterpret_cast<ushort4*>(comb + elem) = o;
}

// ---- main: one wave per batch element ----
// lane l<32: stm side, dims [8l, 8l+8); lane l>=32: nstm side, dims [8(l-32), ...).
// Per feature, one dwordx4 per lane fetches 8 bf16 weights; lanes 0-31 read the
// stm row, lanes 32-63 the nstm row -> both 512B rows in one wave instruction.
__global__ __launch_bounds__(256) void nnue_comb_kernel(
    const float* __restrict__ values,
    const int*   __restrict__ stm_idx,
    const int*   __restrict__ nstm_idx,
    const float* __restrict__ ft_b,
    const float* __restrict__ fft_b,
    const unsigned short* __restrict__ comb,
    const float* __restrict__ out_w,
    const float* __restrict__ out_b,
    float*       __restrict__ out,
    int batch)
{
    const int gtid = blockIdx.x * blockDim.x + threadIdx.x;
    const int b    = gtid >> 6;
    const int lane = threadIdx.x & 63;
    if (b >= batch) return;

    float v_reg = 0.0f;
    int   i_reg = 0;
    if (lane < kMaxF) {
        v_reg = values[b * kMaxF + lane];
        i_reg = stm_idx[b * kMaxF + lane];
    } else {
        i_reg = nstm_idx[b * kMaxF + (lane - kMaxF)];
    }

    const int dbase = (lane & 31) * 8;   // first of 8 owned dims within this side

    float acc[8];
    {
        const float4 b0 = *reinterpret_cast<const float4*>(ft_b + dbase);
        const float4 b1 = *reinterpret_cast<const float4*>(ft_b + dbase + 4);
        const float4 c0 = *reinterpret_cast<const float4*>(fft_b + dbase);
        const float4 c1 = *reinterpret_cast<const float4*>(fft_b + dbase + 4);
        acc[0] = b0.x + c0.x; acc[1] = b0.y + c0.y; acc[2] = b0.z + c0.z; acc[3] = b0.w + c0.w;
        acc[4] = b1.x + c1.x; acc[5] = b1.y + c1.y; acc[6] = b1.z + c1.z; acc[7] = b1.w + c1.w;
    }

    const int side_sel = lane & 32;   // 0 for stm lanes, 32 for nstm lanes

#pragma unroll 8
    for (int f = 0; f < kMaxF; ++f) {
        const float v   = __shfl(v_reg, f, 64);
        const int   idx = __shfl(i_reg, f + side_sel, 64);
        const uint4 raw = *reinterpret_cast<const uint4*>(comb + idx * kFtOut + dbase);
        const float w0 = __uint_as_float(raw.x << 16);
        const float w1 = __uint_as_float(raw.x & 0xffff0000u);
        const float w2 = __uint_as_float(raw.y << 16);
        const float w3 = __uint_as_float(raw.y & 0xffff0000u);
        const float w4 = __uint_as_float(raw.z << 16);
        const float w5 = __uint_as_float(raw.z & 0xffff0000u);
        const float w6 = __uint_as_float(raw.w << 16);
        const float w7 = __uint_as_float(raw.w & 0xffff0000u);
        acc[0] = fmaf(v, w0, acc[0]);
        acc[1] = fmaf(v, w1, acc[1]);
        acc[2] = fmaf(v, w2, acc[2]);
        acc[3] = fmaf(v, w3, acc[3]);
        acc[4] = fmaf(v, w4, acc[4]);
        acc[5] = fmaf(v, w5, acc[5]);
        acc[6] = fmaf(v, w6, acc[6]);
        acc[7] = fmaf(v, w7, acc[7]);
    }

    // out_w offset: stm lane l -> 8l; nstm lane l -> 256 + 8(l-32) = 8l. Uniform!
    const float4 ow0 = *reinterpret_cast<const float4*>(out_w + 8 * lane);
    const float4 ow1 = *reinterpret_cast<const float4*>(out_w + 8 * lane + 4);

    float p = clip01(acc[0]) * ow0.x + clip01(acc[1]) * ow0.y
            + clip01(acc[2]) * ow0.z + clip01(acc[3]) * ow0.w
            + clip01(acc[4]) * ow1.x + clip01(acc[5]) * ow1.y
            + clip01(acc[6]) * ow1.z + clip01(acc[7]) * ow1.w;

#pragma unroll
    for (int off = 32; off > 0; off >>= 1)
        p += __shfl_down(p, off, 64);

    if (lane == 0) {
        const float x = p + out_b[0];
        out[b] = 1.0f / (1.0f + expf(-x));
    }
}

// ---- fallback (R1 kernel): direct fp32 gathers, used only if ws too small ----
__device__ __forceinline__ void fma4(float4& acc, float v, const float4& a, const float4& b) {
    acc.x = fmaf(v, a.x + b.x, acc.x);
    acc.y = fmaf(v, a.y + b.y, acc.y);
    acc.z = fmaf(v, a.z + b.z, acc.z);
    acc.w = fmaf(v, a.w + b.w, acc.w);
}

__global__ __launch_bounds__(256) void nnue_halfkp_fallback(
    const float* __restrict__ values,
    const int*   __restrict__ stm_idx,
    const int*   __restrict__ nstm_idx,
    const float* __restrict__ ft_w,
    const float* __restrict__ ft_b,
    const float* __restrict__ fft_w,
    const float* __restrict__ fft_b,
    const float* __restrict__ out_w,
    const float* __restrict__ out_b,
    float*       __restrict__ out,
    int batch)
{
    const int gtid = blockIdx.x * blockDim.x + threadIdx.x;
    const int b    = gtid >> 6;
    const int lane = threadIdx.x & 63;
    if (b >= batch) return;

    float v_reg = 0.0f;
    int   i_reg = 0;
    if (lane < kMaxF) {
        v_reg = values[b * kMaxF + lane];
        i_reg = stm_idx[b * kMaxF + lane];
    } else {
        i_reg = nstm_idx[b * kMaxF + (lane - kMaxF)];
    }

    const float4* ftw4  = reinterpret_cast<const float4*>(ft_w);
    const float4* fftw4 = reinterpret_cast<const float4*>(fft_w);

    const float4 fb  = reinterpret_cast<const float4*>(ft_b)[lane];
    const float4 ffb = reinterpret_cast<const float4*>(fft_b)[lane];
    float4 acc_s = make_float4(fb.x + ffb.x, fb.y + ffb.y, fb.z + ffb.z, fb.w + ffb.w);
    float4 acc_n = acc_s;

#pragma unroll 8
    for (int f = 0; f < kMaxF; ++f) {
        const float v  = __shfl(v_reg, f, 64);
        const int   is = __shfl(i_reg, f, 64);
        const int   in = __shfl(i_reg, f + kMaxF, 64);
        const float4 as = ftw4[is * 64 + lane];
        const float4 bs = fftw4[(is % kNumFFT) * 64 + lane];
        const float4 an = ftw4[in * 64 + lane];
        const float4 bn = fftw4[(in % kNumFFT) * 64 + lane];
        fma4(acc_s, v, as, bs);
        fma4(acc_n, v, an, bn);
    }

    const float4* ow4 = reinterpret_cast<const float4*>(out_w);
    const float4 ws = ow4[lane];
    const float4 wn = ow4[64 + lane];

    float p = clip01(acc_s.x) * ws.x + clip01(acc_s.y) * ws.y
            + clip01(acc_s.z) * ws.z + clip01(acc_s.w) * ws.w
            + clip01(acc_n.x) * wn.x + clip01(acc_n.y) * wn.y
            + clip01(acc_n.z) * wn.z + clip01(acc_n.w) * wn.w;

#pragma unroll
    for (int off = 32; off > 0; off >>= 1)
        p += __shfl_down(p, off, 64);

    if (lane == 0) {
        const float x = p + out_b[0];
        out[b] = 1.0f / (1.0f + expf(-x));
    }
}

extern "C" void kernel_launch(void* const* d_in, const int* in_sizes, int n_in,
                              void* d_out, int out_size, void* d_ws, size_t ws_size,
                              hipStream_t stream) {
    const float* values = (const float*)d_in[0];
    const int*   stm    = (const int*)  d_in[1];
    const int*   nstm   = (const int*)  d_in[2];
    const float* ft_w   = (const float*)d_in[3];
    const float* ft_b   = (const float*)d_in[4];
    const float* fft_w  = (const float*)d_in[5];
    const float* fft_b  = (const float*)d_in[6];
    const float* out_w  = (const float*)d_in[7];
    const float* out_b  = (const float*)d_in[8];
    float* out = (float*)d_out;

    const int batch = in_sizes[0] / kMaxF;   // 8192
    const size_t comb_bytes = (size_t)kNumFT * kFtOut * sizeof(unsigned short); // ~21 MB

    if (ws_size >= comb_bytes) {
        unsigned short* comb = (unsigned short*)d_ws;
        const int total4 = kNumFT * kFtOut / 4;
        hipLaunchKernelGGL(prep_comb_kernel, dim3((total4 + 255) / 256), dim3(256), 0, stream,
                           ft_w, fft_w, comb, total4);
        const int blocks = (batch * 64 + 255) / 256;
        hipLaunchKernelGGL(nnue_comb_kernel, dim3(blocks), dim3(256), 0, stream,
                           values, stm, nstm, ft_b, fft_b, comb, out_w, out_b, out, batch);
    } else {
        const int blocks = (batch * 64 + 255) / 256;
        hipLaunchKernelGGL(nnue_halfkp_fallback, dim3(blocks), dim3(256), 0, stream,
                           values, stm, nstm, ft_w, ft_b, fft_w, fft_b, out_w, out_b, out, batch);
    }
}

// Round 3
// 115.598 us; speedup vs baseline: 1.3844x; 1.1292x over previous
//
#include <hip/hip_runtime.h>
#include <math.h>

constexpr int kMaxF   = 32;
constexpr int kFtOut  = 256;
constexpr int kNumFFT = 640;
constexpr int kNumFT  = 40960;

__device__ __forceinline__ float clip01(float x) {
    return fminf(fmaxf(x, 0.0f), 1.0f);
}

// ---- prep: one wave per table row ----
// comb row w[d] = ft_w[row][d] + fft_w[row%640][d]; s = max|w|/127;
// qtab[row][d] = rint(w[d]/s) as int8; scales[row] = s.
__global__ __launch_bounds__(256) void prep_q8_kernel(
    const float* __restrict__ ft_w,
    const float* __restrict__ fft_w,
    signed char* __restrict__ qtab,
    float*       __restrict__ scales,
    int rows)
{
    const int wid  = (blockIdx.x * blockDim.x + threadIdx.x) >> 6;
    const int lane = threadIdx.x & 63;
    if (wid >= rows) return;
    const int d = lane * 4;   // 64 lanes x 4 dims = 256
    const float4 a = *reinterpret_cast<const float4*>(ft_w + wid * kFtOut + d);
    const float4 c = *reinterpret_cast<const float4*>(fft_w + (wid % kNumFFT) * kFtOut + d);
    const float w0 = a.x + c.x, w1 = a.y + c.y, w2 = a.z + c.z, w3 = a.w + c.w;

    float m = fmaxf(fmaxf(fabsf(w0), fabsf(w1)), fmaxf(fabsf(w2), fabsf(w3)));
#pragma unroll
    for (int off = 32; off > 0; off >>= 1)
        m = fmaxf(m, __shfl_xor(m, off, 64));

    const float s_inv = (m > 0.0f) ? 127.0f / m : 0.0f;
    int q0 = (int)rintf(w0 * s_inv);
    int q1 = (int)rintf(w1 * s_inv);
    int q2 = (int)rintf(w2 * s_inv);
    int q3 = (int)rintf(w3 * s_inv);
    q0 = min(max(q0, -127), 127);
    q1 = min(max(q1, -127), 127);
    q2 = min(max(q2, -127), 127);
    q3 = min(max(q3, -127), 127);
    const unsigned int pack = (unsigned int)(q0 & 0xff)
                            | ((unsigned int)(q1 & 0xff) << 8)
                            | ((unsigned int)(q2 & 0xff) << 16)
                            | ((unsigned int)(q3 & 0xff) << 24);
    *reinterpret_cast<unsigned int*>(qtab + (size_t)wid * kFtOut + d) = pack;
    if (lane == 0) scales[wid] = (m > 0.0f) ? m / 127.0f : 0.0f;
}

// ---- main: one wave per batch element ----
// lane l<32: stm side, dims [8l, 8l+8); lane l>=32: nstm side.
// Per-row scale is folded into the broadcast value before the loop, so the
// K-loop is pure int8 row loads (int2 = 8 dims/lane) + unpack + fma.
__global__ __launch_bounds__(256) void nnue_q8_kernel(
    const float* __restrict__ values,
    const int*   __restrict__ stm_idx,
    const int*   __restrict__ nstm_idx,
    const float* __restrict__ ft_b,
    const float* __restrict__ fft_b,
    const signed char* __restrict__ qtab,
    const float* __restrict__ scales,
    const float* __restrict__ out_w,
    const float* __restrict__ out_b,
    float*       __restrict__ out,
    int batch)
{
    const int gtid = blockIdx.x * blockDim.x + threadIdx.x;
    const int b    = gtid >> 6;
    const int lane = threadIdx.x & 63;
    if (b >= batch) return;

    // lanes [0,32): values + stm idx for feature `lane`
    // lanes [32,64): nstm idx for feature `lane-32`
    float v_reg = 0.0f;
    int   i_reg = 0;
    if (lane < kMaxF) {
        v_reg = values[b * kMaxF + lane];
        i_reg = stm_idx[b * kMaxF + lane];
    } else {
        i_reg = nstm_idx[b * kMaxF + (lane - kMaxF)];
    }

    // Pre-scale: lane l holds v[l&31] * scales[idx_l] — one 160KB-table gather
    // per wave, zero scale work inside the K-loop.
    const float v_full = __shfl(v_reg, lane & 31, 64);
    const float vp     = v_full * scales[i_reg];

    const int dbase    = (lane & 31) * 8;
    const int side_sel = lane & 32;

    float acc[8];
    {
        const float4 b0 = *reinterpret_cast<const float4*>(ft_b + dbase);
        const float4 b1 = *reinterpret_cast<const float4*>(ft_b + dbase + 4);
        const float4 c0 = *reinterpret_cast<const float4*>(fft_b + dbase);
        const float4 c1 = *reinterpret_cast<const float4*>(fft_b + dbase + 4);
        acc[0] = b0.x + c0.x; acc[1] = b0.y + c0.y; acc[2] = b0.z + c0.z; acc[3] = b0.w + c0.w;
        acc[4] = b1.x + c1.x; acc[5] = b1.y + c1.y; acc[6] = b1.z + c1.z; acc[7] = b1.w + c1.w;
    }

#pragma unroll 16
    for (int f = 0; f < kMaxF; ++f) {
        const float vs  = __shfl(vp,    f + side_sel, 64);
        const int   idx = __shfl(i_reg, f + side_sel, 64);
        const int2 raw = *reinterpret_cast<const int2*>(qtab + (size_t)idx * kFtOut + dbase);
        const int x = raw.x, y = raw.y;
        acc[0] = fmaf(vs, (float)((x << 24) >> 24), acc[0]);
        acc[1] = fmaf(vs, (float)((x << 16) >> 24), acc[1]);
        acc[2] = fmaf(vs, (float)((x <<  8) >> 24), acc[2]);
        acc[3] = fmaf(vs, (float)( x        >> 24), acc[3]);
        acc[4] = fmaf(vs, (float)((y << 24) >> 24), acc[4]);
        acc[5] = fmaf(vs, (float)((y << 16) >> 24), acc[5]);
        acc[6] = fmaf(vs, (float)((y <<  8) >> 24), acc[6]);
        acc[7] = fmaf(vs, (float)( y        >> 24), acc[7]);
    }

    // out_w offset: stm lane l -> 8l; nstm lane l -> 256 + 8(l-32) = 8l. Uniform.
    const float4 ow0 = *reinterpret_cast<const float4*>(out_w + 8 * lane);
    const float4 ow1 = *reinterpret_cast<const float4*>(out_w + 8 * lane + 4);

    float p = clip01(acc[0]) * ow0.x + clip01(acc[1]) * ow0.y
            + clip01(acc[2]) * ow0.z + clip01(acc[3]) * ow0.w
            + clip01(acc[4]) * ow1.x + clip01(acc[5]) * ow1.y
            + clip01(acc[6]) * ow1.z + clip01(acc[7]) * ow1.w;

#pragma unroll
    for (int off = 32; off > 0; off >>= 1)
        p += __shfl_down(p, off, 64);

    if (lane == 0) {
        const float x = p + out_b[0];
        out[b] = 1.0f / (1.0f + expf(-x));
    }
}

// ---- fallback: direct fp32 gathers (only if ws too small; exact) ----
__device__ __forceinline__ void fma4(float4& acc, float v, const float4& a, const float4& b) {
    acc.x = fmaf(v, a.x + b.x, acc.x);
    acc.y = fmaf(v, a.y + b.y, acc.y);
    acc.z = fmaf(v, a.z + b.z, acc.z);
    acc.w = fmaf(v, a.w + b.w, acc.w);
}

__global__ __launch_bounds__(256) void nnue_halfkp_fallback(
    const float* __restrict__ values,
    const int*   __restrict__ stm_idx,
    const int*   __restrict__ nstm_idx,
    const float* __restrict__ ft_w,
    const float* __restrict__ ft_b,
    const float* __restrict__ fft_w,
    const float* __restrict__ fft_b,
    const float* __restrict__ out_w,
    const float* __restrict__ out_b,
    float*       __restrict__ out,
    int batch)
{
    const int gtid = blockIdx.x * blockDim.x + threadIdx.x;
    const int b    = gtid >> 6;
    const int lane = threadIdx.x & 63;
    if (b >= batch) return;

    float v_reg = 0.0f;
    int   i_reg = 0;
    if (lane < kMaxF) {
        v_reg = values[b * kMaxF + lane];
        i_reg = stm_idx[b * kMaxF + lane];
    } else {
        i_reg = nstm_idx[b * kMaxF + (lane - kMaxF)];
    }

    const float4* ftw4  = reinterpret_cast<const float4*>(ft_w);
    const float4* fftw4 = reinterpret_cast<const float4*>(fft_w);

    const float4 fb  = reinterpret_cast<const float4*>(ft_b)[lane];
    const float4 ffb = reinterpret_cast<const float4*>(fft_b)[lane];
    float4 acc_s = make_float4(fb.x + ffb.x, fb.y + ffb.y, fb.z + ffb.z, fb.w + ffb.w);
    float4 acc_n = acc_s;

#pragma unroll 8
    for (int f = 0; f < kMaxF; ++f) {
        const float v  = __shfl(v_reg, f, 64);
        const int   is = __shfl(i_reg, f, 64);
        const int   in = __shfl(i_reg, f + kMaxF, 64);
        const float4 as = ftw4[is * 64 + lane];
        const float4 bs = fftw4[(is % kNumFFT) * 64 + lane];
        const float4 an = ftw4[in * 64 + lane];
        const float4 bn = fftw4[(in % kNumFFT) * 64 + lane];
        fma4(acc_s, v, as, bs);
        fma4(acc_n, v, an, bn);
    }

    const float4* ow4 = reinterpret_cast<const float4*>(out_w);
    const float4 ws = ow4[lane];
    const float4 wn = ow4[64 + lane];

    float p = clip01(acc_s.x) * ws.x + clip01(acc_s.y) * ws.y
            + clip01(acc_s.z) * ws.z + clip01(acc_s.w) * ws.w
            + clip01(acc_n.x) * wn.x + clip01(acc_n.y) * wn.y
            + clip01(acc_n.z) * wn.z + clip01(acc_n.w) * wn.w;

#pragma unroll
    for (int off = 32; off > 0; off >>= 1)
        p += __shfl_down(p, off, 64);

    if (lane == 0) {
        const float x = p + out_b[0];
        out[b] = 1.0f / (1.0f + expf(-x));
    }
}

extern "C" void kernel_launch(void* const* d_in, const int* in_sizes, int n_in,
                              void* d_out, int out_size, void* d_ws, size_t ws_size,
                              hipStream_t stream) {
    const float* values = (const float*)d_in[0];
    const int*   stm    = (const int*)  d_in[1];
    const int*   nstm   = (const int*)  d_in[2];
    const float* ft_w   = (const float*)d_in[3];
    const float* ft_b   = (const float*)d_in[4];
    const float* fft_w  = (const float*)d_in[5];
    const float* fft_b  = (const float*)d_in[6];
    const float* out_w  = (const float*)d_in[7];
    const float* out_b  = (const float*)d_in[8];
    float* out = (float*)d_out;

    const int batch = in_sizes[0] / kMaxF;   // 8192
    const size_t qtab_bytes  = (size_t)kNumFT * kFtOut;            // 10 MB
    const size_t scale_bytes = (size_t)kNumFT * sizeof(float);     // 160 KB

    if (ws_size >= qtab_bytes + scale_bytes) {
        signed char* qtab = (signed char*)d_ws;
        float* scales = (float*)((char*)d_ws + qtab_bytes);
        const int prep_blocks = (kNumFT * 64 + 255) / 256;
        hipLaunchKernelGGL(prep_q8_kernel, dim3(prep_blocks), dim3(256), 0, stream,
                           ft_w, fft_w, qtab, scales, kNumFT);
        const int blocks = (batch * 64 + 255) / 256;
        hipLaunchKernelGGL(nnue_q8_kernel, dim3(blocks), dim3(256), 0, stream,
                           values, stm, nstm, ft_b, fft_b, qtab, scales, out_w, out_b, out, batch);
    } else {
        const int blocks = (batch * 64 + 255) / 256;
        hipLaunchKernelGGL(nnue_halfkp_fallback, dim3(blocks), dim3(256), 0, stream,
                           values, stm, nstm, ft_w, ft_b, fft_w, fft_b, out_w, out_b, out, batch);
    }
}

// Round 4
// 114.879 us; speedup vs baseline: 1.3930x; 1.0063x over previous
//
#include <hip/hip_runtime.h>
#include <math.h>

constexpr int kMaxF   = 32;
constexpr int kFtOut  = 256;
constexpr int kNumFFT = 640;
constexpr int kNumFT  = 40960;
constexpr int kRowB   = kFtOut / 2;   // int4: 128 bytes per row

__device__ __forceinline__ float clip01(float x) {
    return fminf(fmaxf(x, 0.0f), 1.0f);
}

// ---- prep: one wave per table row ----
// w[d] = ft_w[row][d] + fft_w[row%640][d]; m = max|w| over row; scale = m/7;
// qtab nibble k of byte j encodes dim 2j+(k?1:0): q = clamp(rint(w/scale),-7,7).
__global__ __launch_bounds__(256) void prep_q4_kernel(
    const float* __restrict__ ft_w,
    const float* __restrict__ fft_w,
    unsigned short* __restrict__ qtab,   // 2 bytes = 4 nibbles = 4 dims per lane
    float*       __restrict__ scales,
    int rows)
{
    const int wid  = (blockIdx.x * blockDim.x + threadIdx.x) >> 6;
    const int lane = threadIdx.x & 63;
    if (wid >= rows) return;
    const int d = lane * 4;   // 64 lanes x 4 dims = 256
    const float4 a = *reinterpret_cast<const float4*>(ft_w + wid * kFtOut + d);
    const float4 c = *reinterpret_cast<const float4*>(fft_w + (wid % kNumFFT) * kFtOut + d);
    const float w0 = a.x + c.x, w1 = a.y + c.y, w2 = a.z + c.z, w3 = a.w + c.w;

    float m = fmaxf(fmaxf(fabsf(w0), fabsf(w1)), fmaxf(fabsf(w2), fabsf(w3)));
#pragma unroll
    for (int off = 32; off > 0; off >>= 1)
        m = fmaxf(m, __shfl_xor(m, off, 64));

    const float s_inv = (m > 0.0f) ? 7.0f / m : 0.0f;
    int q0 = min(max((int)rintf(w0 * s_inv), -7), 7);
    int q1 = min(max((int)rintf(w1 * s_inv), -7), 7);
    int q2 = min(max((int)rintf(w2 * s_inv), -7), 7);
    int q3 = min(max((int)rintf(w3 * s_inv), -7), 7);
    const unsigned int pack = (unsigned int)(q0 & 0xf)
                            | ((unsigned int)(q1 & 0xf) << 4)
                            | ((unsigned int)(q2 & 0xf) << 8)
                            | ((unsigned int)(q3 & 0xf) << 12);
    // lane's 4 dims start at byte d/2 = lane*2 -> ushort index lane within row
    qtab[(size_t)wid * (kRowB / 2) + lane] = (unsigned short)pack;
    if (lane == 0) scales[wid] = (m > 0.0f) ? m / 7.0f : 0.0f;
}

// ---- main: one wave per batch element ----
// lane l<32: stm side, dims [8l, 8l+8); lane l>=32: nstm side.
// Per-row scale folded into the broadcast value; K-loop is one dword int4-row
// load per lane (8 dims) + bfe/cvt unpack + fma.
__global__ __launch_bounds__(256) void nnue_q4_kernel(
    const float* __restrict__ values,
    const int*   __restrict__ stm_idx,
    const int*   __restrict__ nstm_idx,
    const float* __restrict__ ft_b,
    const float* __restrict__ fft_b,
    const unsigned char* __restrict__ qtab,
    const float* __restrict__ scales,
    const float* __restrict__ out_w,
    const float* __restrict__ out_b,
    float*       __restrict__ out,
    int batch)
{
    const int gtid = blockIdx.x * blockDim.x + threadIdx.x;
    const int b    = gtid >> 6;
    const int lane = threadIdx.x & 63;
    if (b >= batch) return;

    float v_reg = 0.0f;
    int   i_reg = 0;
    if (lane < kMaxF) {
        v_reg = values[b * kMaxF + lane];
        i_reg = stm_idx[b * kMaxF + lane];
    } else {
        i_reg = nstm_idx[b * kMaxF + (lane - kMaxF)];
    }

    // vp[lane] = value(feat = lane&31) * scale(row = idx of this lane's combo)
    const float v_full = __shfl(v_reg, lane & 31, 64);
    const float vp     = v_full * scales[i_reg];

    const int dbase    = (lane & 31) * 8;      // 8 dims per lane
    const int qoff     = (lane & 31) * 4;      // byte offset within 128B row
    const int side_sel = lane & 32;

    float acc[8];
    {
        const float4 b0 = *reinterpret_cast<const float4*>(ft_b + dbase);
        const float4 b1 = *reinterpret_cast<const float4*>(ft_b + dbase + 4);
        const float4 c0 = *reinterpret_cast<const float4*>(fft_b + dbase);
        const float4 c1 = *reinterpret_cast<const float4*>(fft_b + dbase + 4);
        acc[0] = b0.x + c0.x; acc[1] = b0.y + c0.y; acc[2] = b0.z + c0.z; acc[3] = b0.w + c0.w;
        acc[4] = b1.x + c1.x; acc[5] = b1.y + c1.y; acc[6] = b1.z + c1.z; acc[7] = b1.w + c1.w;
    }

#pragma unroll 16
    for (int f = 0; f < kMaxF; ++f) {
        const float vs  = __shfl(vp,    f + side_sel, 64);
        const int   idx = __shfl(i_reg, f + side_sel, 64);
        const unsigned int w =
            *reinterpret_cast<const unsigned int*>(qtab + (size_t)idx * kRowB + qoff);
        // nibble k -> dim dbase+k, signed 4-bit: (int)(w << (28-4k)) >> 28
        acc[0] = fmaf(vs, (float)(((int)(w << 28)) >> 28), acc[0]);
        acc[1] = fmaf(vs, (float)(((int)(w << 24)) >> 28), acc[1]);
        acc[2] = fmaf(vs, (float)(((int)(w << 20)) >> 28), acc[2]);
        acc[3] = fmaf(vs, (float)(((int)(w << 16)) >> 28), acc[3]);
        acc[4] = fmaf(vs, (float)(((int)(w << 12)) >> 28), acc[4]);
        acc[5] = fmaf(vs, (float)(((int)(w <<  8)) >> 28), acc[5]);
        acc[6] = fmaf(vs, (float)(((int)(w <<  4)) >> 28), acc[6]);
        acc[7] = fmaf(vs, (float)(((int) w       ) >> 28), acc[7]);
    }

    // out_w offset: stm lane l -> 8l; nstm lane l -> 256 + 8(l-32) = 8l. Uniform.
    const float4 ow0 = *reinterpret_cast<const float4*>(out_w + 8 * lane);
    const float4 ow1 = *reinterpret_cast<const float4*>(out_w + 8 * lane + 4);

    float p = clip01(acc[0]) * ow0.x + clip01(acc[1]) * ow0.y
            + clip01(acc[2]) * ow0.z + clip01(acc[3]) * ow0.w
            + clip01(acc[4]) * ow1.x + clip01(acc[5]) * ow1.y
            + clip01(acc[6]) * ow1.z + clip01(acc[7]) * ow1.w;

#pragma unroll
    for (int off = 32; off > 0; off >>= 1)
        p += __shfl_down(p, off, 64);

    if (lane == 0) {
        const float x = p + out_b[0];
        out[b] = 1.0f / (1.0f + expf(-x));
    }
}

// ---- fallback: direct fp32 gathers (only if ws too small; exact) ----
__device__ __forceinline__ void fma4(float4& acc, float v, const float4& a, const float4& b) {
    acc.x = fmaf(v, a.x + b.x, acc.x);
    acc.y = fmaf(v, a.y + b.y, acc.y);
    acc.z = fmaf(v, a.z + b.z, acc.z);
    acc.w = fmaf(v, a.w + b.w, acc.w);
}

__global__ __launch_bounds__(256) void nnue_halfkp_fallback(
    const float* __restrict__ values,
    const int*   __restrict__ stm_idx,
    const int*   __restrict__ nstm_idx,
    const float* __restrict__ ft_w,
    const float* __restrict__ ft_b,
    const float* __restrict__ fft_w,
    const float* __restrict__ fft_b,
    const float* __restrict__ out_w,
    const float* __restrict__ out_b,
    float*       __restrict__ out,
    int batch)
{
    const int gtid = blockIdx.x * blockDim.x + threadIdx.x;
    const int b    = gtid >> 6;
    const int lane = threadIdx.x & 63;
    if (b >= batch) return;

    float v_reg = 0.0f;
    int   i_reg = 0;
    if (lane < kMaxF) {
        v_reg = values[b * kMaxF + lane];
        i_reg = stm_idx[b * kMaxF + lane];
    } else {
        i_reg = nstm_idx[b * kMaxF + (lane - kMaxF)];
    }

    const float4* ftw4  = reinterpret_cast<const float4*>(ft_w);
    const float4* fftw4 = reinterpret_cast<const float4*>(fft_w);

    const float4 fb  = reinterpret_cast<const float4*>(ft_b)[lane];
    const float4 ffb = reinterpret_cast<const float4*>(fft_b)[lane];
    float4 acc_s = make_float4(fb.x + ffb.x, fb.y + ffb.y, fb.z + ffb.z, fb.w + ffb.w);
    float4 acc_n = acc_s;

#pragma unroll 8
    for (int f = 0; f < kMaxF; ++f) {
        const float v  = __shfl(v_reg, f, 64);
        const int   is = __shfl(i_reg, f, 64);
        const int   in = __shfl(i_reg, f + kMaxF, 64);
        const float4 as = ftw4[is * 64 + lane];
        const float4 bs = fftw4[(is % kNumFFT) * 64 + lane];
        const float4 an = ftw4[in * 64 + lane];
        const float4 bn = fftw4[(in % kNumFFT) * 64 + lane];
        fma4(acc_s, v, as, bs);
        fma4(acc_n, v, an, bn);
    }

    const float4* ow4 = reinterpret_cast<const float4*>(out_w);
    const float4 ws = ow4[lane];
    const float4 wn = ow4[64 + lane];

    float p = clip01(acc_s.x) * ws.x + clip01(acc_s.y) * ws.y
            + clip01(acc_s.z) * ws.z + clip01(acc_s.w) * ws.w
            + clip01(acc_n.x) * wn.x + clip01(acc_n.y) * wn.y
            + clip01(acc_n.z) * wn.z + clip01(acc_n.w) * wn.w;

#pragma unroll
    for (int off = 32; off > 0; off >>= 1)
        p += __shfl_down(p, off, 64);

    if (lane == 0) {
        const float x = p + out_b[0];
        out[b] = 1.0f / (1.0f + expf(-x));
    }
}

extern "C" void kernel_launch(void* const* d_in, const int* in_sizes, int n_in,
                              void* d_out, int out_size, void* d_ws, size_t ws_size,
                              hipStream_t stream) {
    const float* values = (const float*)d_in[0];
    const int*   stm    = (const int*)  d_in[1];
    const int*   nstm   = (const int*)  d_in[2];
    const float* ft_w   = (const float*)d_in[3];
    const float* ft_b   = (const float*)d_in[4];
    const float* fft_w  = (const float*)d_in[5];
    const float* fft_b  = (const float*)d_in[6];
    const float* out_w  = (const float*)d_in[7];
    const float* out_b  = (const float*)d_in[8];
    float* out = (float*)d_out;

    const int batch = in_sizes[0] / kMaxF;   // 8192
    const size_t qtab_bytes  = (size_t)kNumFT * kRowB;             // 5 MB
    const size_t scale_bytes = (size_t)kNumFT * sizeof(float);     // 160 KB

    if (ws_size >= qtab_bytes + scale_bytes) {
        unsigned char* qtab = (unsigned char*)d_ws;
        float* scales = (float*)((char*)d_ws + qtab_bytes);
        const int prep_blocks = (kNumFT * 64 + 255) / 256;
        hipLaunchKernelGGL(prep_q4_kernel, dim3(prep_blocks), dim3(256), 0, stream,
                           ft_w, fft_w, (unsigned short*)qtab, scales, kNumFT);
        const int blocks = (batch * 64 + 255) / 256;
        hipLaunchKernelGGL(nnue_q4_kernel, dim3(blocks), dim3(256), 0, stream,
                           values, stm, nstm, ft_b, fft_b, qtab, scales, out_w, out_b, out, batch);
    } else {
        const int blocks = (batch * 64 + 255) / 256;
        hipLaunchKernelGGL(nnue_halfkp_fallback, dim3(blocks), dim3(256), 0, stream,
                           values, stm, nstm, ft_w, ft_b, fft_w, fft_b, out_w, out_b, out, batch);
    }
}

// Round 5
// 113.751 us; speedup vs baseline: 1.4069x; 1.0099x over previous
//
#include <hip/hip_runtime.h>
#include <math.h>

constexpr int kMaxF   = 32;
constexpr int kFtOut  = 256;
constexpr int kNumFFT = 640;
constexpr int kNumFT  = 40960;
constexpr int kRowB   = kFtOut;   // fp8: 256 bytes per row

typedef float v2f __attribute__((ext_vector_type(2)));

__device__ __forceinline__ float clip01(float x) {
    return fminf(fmaxf(x, 0.0f), 1.0f);
}

// ---- prep: one wave per table row ----
// qtab[row][d] = fp8_e4m3(ft_w[row][d] + fft_w[row%640][d]); 4 dims per lane.
__global__ __launch_bounds__(256) void prep_fp8_kernel(
    const float* __restrict__ ft_w,
    const float* __restrict__ fft_w,
    unsigned int* __restrict__ qtab,   // 1 dword = 4 fp8 = 4 dims per lane
    int rows)
{
    const int wid  = (blockIdx.x * blockDim.x + threadIdx.x) >> 6;
    const int lane = threadIdx.x & 63;
    if (wid >= rows) return;
    const int d = lane * 4;   // 64 lanes x 4 dims = 256
    const float4 a = *reinterpret_cast<const float4*>(ft_w + wid * kFtOut + d);
    const float4 c = *reinterpret_cast<const float4*>(fft_w + (wid % kNumFFT) * kFtOut + d);
    const float w0 = a.x + c.x, w1 = a.y + c.y, w2 = a.z + c.z, w3 = a.w + c.w;

    // byte k of dword = dim d+k (cvt_pk packs src0->byte0, src1->byte1 of word)
    int pk = __builtin_amdgcn_cvt_pk_fp8_f32(w0, w1, 0, false);   // low word
    pk     = __builtin_amdgcn_cvt_pk_fp8_f32(w2, w3, pk, true);   // high word
    qtab[(size_t)wid * (kRowB / 4) + lane] = (unsigned int)pk;
}

// ---- main: one wave per batch element ----
// lane l<32: stm side, dims [8l, 8l+8); lane l>=32: nstm side.
// K-loop: 2 shfl + one dwordx2 fp8-row load (8 dims) + 4 HW cvt + 8 fma.
__global__ __launch_bounds__(256) void nnue_fp8_kernel(
    const float* __restrict__ values,
    const int*   __restrict__ stm_idx,
    const int*   __restrict__ nstm_idx,
    const float* __restrict__ ft_b,
    const float* __restrict__ fft_b,
    const unsigned char* __restrict__ qtab,
    const float* __restrict__ out_w,
    const float* __restrict__ out_b,
    float*       __restrict__ out,
    int batch)
{
    const int gtid = blockIdx.x * blockDim.x + threadIdx.x;
    const int b    = gtid >> 6;
    const int lane = threadIdx.x & 63;
    if (b >= batch) return;

    // lanes [0,32): values + stm idx for feature `lane`
    // lanes [32,64): nstm idx for feature `lane-32`
    float v_reg = 0.0f;
    int   i_reg = 0;
    if (lane < kMaxF) {
        v_reg = values[b * kMaxF + lane];
        i_reg = stm_idx[b * kMaxF + lane];
    } else {
        i_reg = nstm_idx[b * kMaxF + (lane - kMaxF)];
    }

    const int dbase    = (lane & 31) * 8;   // 8 dims per lane; also byte offset in row
    const int side_sel = lane & 32;

    float acc[8];
    {
        const float4 b0 = *reinterpret_cast<const float4*>(ft_b + dbase);
        const float4 b1 = *reinterpret_cast<const float4*>(ft_b + dbase + 4);
        const float4 c0 = *reinterpret_cast<const float4*>(fft_b + dbase);
        const float4 c1 = *reinterpret_cast<const float4*>(fft_b + dbase + 4);
        acc[0] = b0.x + c0.x; acc[1] = b0.y + c0.y; acc[2] = b0.z + c0.z; acc[3] = b0.w + c0.w;
        acc[4] = b1.x + c1.x; acc[5] = b1.y + c1.y; acc[6] = b1.z + c1.z; acc[7] = b1.w + c1.w;
    }

#pragma unroll 16
    for (int f = 0; f < kMaxF; ++f) {
        const float vs  = __shfl(v_reg, f, 64);              // values shared by both sides
        const int   idx = __shfl(i_reg, f + side_sel, 64);
        const uint2 raw = *reinterpret_cast<const uint2*>(qtab + (size_t)idx * kRowB + dbase);
        const v2f p0 = __builtin_amdgcn_cvt_pk_f32_fp8((int)raw.x, false);  // dims +0,+1
        const v2f p1 = __builtin_amdgcn_cvt_pk_f32_fp8((int)raw.x, true);   // dims +2,+3
        const v2f p2 = __builtin_amdgcn_cvt_pk_f32_fp8((int)raw.y, false);  // dims +4,+5
        const v2f p3 = __builtin_amdgcn_cvt_pk_f32_fp8((int)raw.y, true);   // dims +6,+7
        acc[0] = fmaf(vs, p0.x, acc[0]);
        acc[1] = fmaf(vs, p0.y, acc[1]);
        acc[2] = fmaf(vs, p1.x, acc[2]);
        acc[3] = fmaf(vs, p1.y, acc[3]);
        acc[4] = fmaf(vs, p2.x, acc[4]);
        acc[5] = fmaf(vs, p2.y, acc[5]);
        acc[6] = fmaf(vs, p3.x, acc[6]);
        acc[7] = fmaf(vs, p3.y, acc[7]);
    }

    // out_w offset: stm lane l -> 8l; nstm lane l -> 256 + 8(l-32) = 8l. Uniform.
    const float4 ow0 = *reinterpret_cast<const float4*>(out_w + 8 * lane);
    const float4 ow1 = *reinterpret_cast<const float4*>(out_w + 8 * lane + 4);

    float p = clip01(acc[0]) * ow0.x + clip01(acc[1]) * ow0.y
            + clip01(acc[2]) * ow0.z + clip01(acc[3]) * ow0.w
            + clip01(acc[4]) * ow1.x + clip01(acc[5]) * ow1.y
            + clip01(acc[6]) * ow1.z + clip01(acc[7]) * ow1.w;

#pragma unroll
    for (int off = 32; off > 0; off >>= 1)
        p += __shfl_down(p, off, 64);

    if (lane == 0) {
        const float x = p + out_b[0];
        out[b] = 1.0f / (1.0f + expf(-x));
    }
}

// ---- fallback: direct fp32 gathers (only if ws too small; exact) ----
__device__ __forceinline__ void fma4(float4& acc, float v, const float4& a, const float4& b) {
    acc.x = fmaf(v, a.x + b.x, acc.x);
    acc.y = fmaf(v, a.y + b.y, acc.y);
    acc.z = fmaf(v, a.z + b.z, acc.z);
    acc.w = fmaf(v, a.w + b.w, acc.w);
}

__global__ __launch_bounds__(256) void nnue_halfkp_fallback(
    const float* __restrict__ values,
    const int*   __restrict__ stm_idx,
    const int*   __restrict__ nstm_idx,
    const float* __restrict__ ft_w,
    const float* __restrict__ ft_b,
    const float* __restrict__ fft_w,
    const float* __restrict__ fft_b,
    const float* __restrict__ out_w,
    const float* __restrict__ out_b,
    float*       __restrict__ out,
    int batch)
{
    const int gtid = blockIdx.x * blockDim.x + threadIdx.x;
    const int b    = gtid >> 6;
    const int lane = threadIdx.x & 63;
    if (b >= batch) return;

    float v_reg = 0.0f;
    int   i_reg = 0;
    if (lane < kMaxF) {
        v_reg = values[b * kMaxF + lane];
        i_reg = stm_idx[b * kMaxF + lane];
    } else {
        i_reg = nstm_idx[b * kMaxF + (lane - kMaxF)];
    }

    const float4* ftw4  = reinterpret_cast<const float4*>(ft_w);
    const float4* fftw4 = reinterpret_cast<const float4*>(fft_w);

    const float4 fb  = reinterpret_cast<const float4*>(ft_b)[lane];
    const float4 ffb = reinterpret_cast<const float4*>(fft_b)[lane];
    float4 acc_s = make_float4(fb.x + ffb.x, fb.y + ffb.y, fb.z + ffb.z, fb.w + ffb.w);
    float4 acc_n = acc_s;

#pragma unroll 8
    for (int f = 0; f < kMaxF; ++f) {
        const float v  = __shfl(v_reg, f, 64);
        const int   is = __shfl(i_reg, f, 64);
        const int   in = __shfl(i_reg, f + kMaxF, 64);
        const float4 as = ftw4[is * 64 + lane];
        const float4 bs = fftw4[(is % kNumFFT) * 64 + lane];
        const float4 an = ftw4[in * 64 + lane];
        const float4 bn = fftw4[(in % kNumFFT) * 64 + lane];
        fma4(acc_s, v, as, bs);
        fma4(acc_n, v, an, bn);
    }

    const float4* ow4 = reinterpret_cast<const float4*>(out_w);
    const float4 ws = ow4[lane];
    const float4 wn = ow4[64 + lane];

    float p = clip01(acc_s.x) * ws.x + clip01(acc_s.y) * ws.y
            + clip01(acc_s.z) * ws.z + clip01(acc_s.w) * ws.w
            + clip01(acc_n.x) * wn.x + clip01(acc_n.y) * wn.y
            + clip01(acc_n.z) * wn.z + clip01(acc_n.w) * wn.w;

#pragma unroll
    for (int off = 32; off > 0; off >>= 1)
        p += __shfl_down(p, off, 64);

    if (lane == 0) {
        const float x = p + out_b[0];
        out[b] = 1.0f / (1.0f + expf(-x));
    }
}

extern "C" void kernel_launch(void* const* d_in, const int* in_sizes, int n_in,
                              void* d_out, int out_size, void* d_ws, size_t ws_size,
                              hipStream_t stream) {
    const float* values = (const float*)d_in[0];
    const int*   stm    = (const int*)  d_in[1];
    const int*   nstm   = (const int*)  d_in[2];
    const float* ft_w   = (const float*)d_in[3];
    const float* ft_b   = (const float*)d_in[4];
    const float* fft_w  = (const float*)d_in[5];
    const float* fft_b  = (const float*)d_in[6];
    const float* out_w  = (const float*)d_in[7];
    const float* out_b  = (const float*)d_in[8];
    float* out = (float*)d_out;

    const int batch = in_sizes[0] / kMaxF;   // 8192
    const size_t qtab_bytes = (size_t)kNumFT * kRowB;   // 10.5 MB

    if (ws_size >= qtab_bytes) {
        unsigned char* qtab = (unsigned char*)d_ws;
        const int prep_blocks = (kNumFT * 64 + 255) / 256;
        hipLaunchKernelGGL(prep_fp8_kernel, dim3(prep_blocks), dim3(256), 0, stream,
                           ft_w, fft_w, (unsigned int*)qtab, kNumFT);
        const int blocks = (batch * 64 + 255) / 256;
        hipLaunchKernelGGL(nnue_fp8_kernel, dim3(blocks), dim3(256), 0, stream,
                           values, stm, nstm, ft_b, fft_b, qtab, out_w, out_b, out, batch);
    } else {
        const int blocks = (batch * 64 + 255) / 256;
        hipLaunchKernelGGL(nnue_halfkp_fallback, dim3(blocks), dim3(256), 0, stream,
                           values, stm, nstm, ft_w, ft_b, fft_w, fft_b, out_w, out_b, out, batch);
    }
}